// Round 1
// baseline (2258.348 us; speedup 1.0000x reference)
//
#include <hip/hip_runtime.h>
#include <math.h>

#define NN 100000
#define NE 1600000
#define NETOT (NE + NN)
#define FIN 128
#define H1N 8
#define D1 64
#define NC 40

__device__ __forceinline__ float leakyf(float x) { return x >= 0.0f ? x : 0.2f * x; }
__device__ __forceinline__ float eluf(float x)   { return x > 0.0f ? x : expm1f(x); }

// float atomic max via int/uint trick (no NaNs; slots pre-inited to -inf and
// every node has a self-loop so every slot is written at least once)
__device__ __forceinline__ void atomicMaxF(float* a, float v) {
  if (v >= 0.0f) atomicMax((int*)a, __float_as_int(v));
  else           atomicMin((unsigned int*)a, __float_as_uint(v));
}

// ---- edge_index dtype detection (int64 vs int32) ------------------------
__global__ void k_detect(const long long* __restrict__ ei, int* __restrict__ flag) {
  if (blockIdx.x == 0 && threadIdx.x == 0) {
    int is64 = 1;
    for (int i = 0; i < 16; ++i) {
      long long v = ei[i];
      if (v < 0 || v >= NN) is64 = 0;
    }
    *flag = is64;
  }
}

__global__ void k_convert(const void* __restrict__ ei, const int* __restrict__ flag,
                          int* __restrict__ o, int n) {
  int i = blockIdx.x * blockDim.x + threadIdx.x;
  if (i >= n) return;
  o[i] = (*flag) ? (int)((const long long*)ei)[i] : ((const int*)ei)[i];
}

__global__ void k_neginf(float* __restrict__ m, int n) {
  int i = blockIdx.x * blockDim.x + threadIdx.x;
  if (i < n) m[i] = -INFINITY;
}

// ---- layer 1: h1 = x@W1 [N,64]; per-node attention logits [N,8] ---------
__global__ void k_lin1(const float* __restrict__ x, const float* __restrict__ W,
                       const float* __restrict__ aw_s, const float* __restrict__ aw_d,
                       float* __restrict__ h, float* __restrict__ als, float* __restrict__ ald) {
  __shared__ float xs[FIN];
  int n = blockIdx.x, c = threadIdx.x;           // block = 64 threads (1 wave)
  xs[c]      = x[n * FIN + c];
  xs[c + 64] = x[n * FIN + 64 + c];
  __syncthreads();
  float acc = 0.0f;
  #pragma unroll
  for (int k = 0; k < FIN; ++k) acc += xs[k] * W[k * D1 + c];
  h[n * D1 + c] = acc;
  int head = c >> 3, cc = c & 7;
  float s = acc * aw_s[c];                       // a_src1 is [8,8] row-major == [c]
  float d = acc * aw_d[c];
  #pragma unroll
  for (int off = 4; off >= 1; off >>= 1) {
    s += __shfl_xor(s, off, 8);
    d += __shfl_xor(d, off, 8);
  }
  if (cc == 0) { als[n * H1N + head] = s; ald[n * H1N + head] = d; }
}

// ---- layer 1 edge pass A: segment max over dst --------------------------
__global__ void k_max1(const int* __restrict__ ei, const float* __restrict__ als,
                       const float* __restrict__ ald, float* __restrict__ m) {
  int e = blockIdx.x * blockDim.x + threadIdx.x;
  if (e >= NETOT) return;
  int s, d;
  if (e < NE) { s = ei[e]; d = ei[NE + e]; } else { s = e - NE; d = s; }
  const float4* sv = (const float4*)(als + (size_t)s * H1N);
  const float4* dv = (const float4*)(ald + (size_t)d * H1N);
  float4 s0 = sv[0], s1 = sv[1], d0 = dv[0], d1 = dv[1];
  float* md = m + (size_t)d * H1N;
  atomicMaxF(md + 0, leakyf(s0.x + d0.x));
  atomicMaxF(md + 1, leakyf(s0.y + d0.y));
  atomicMaxF(md + 2, leakyf(s0.z + d0.z));
  atomicMaxF(md + 3, leakyf(s0.w + d0.w));
  atomicMaxF(md + 4, leakyf(s1.x + d1.x));
  atomicMaxF(md + 5, leakyf(s1.y + d1.y));
  atomicMaxF(md + 6, leakyf(s1.z + d1.z));
  atomicMaxF(md + 7, leakyf(s1.w + d1.w));
}

// ---- layer 1 edge pass B: denom = segment sum of exp(e - m[dst]) --------
__global__ void k_den1(const int* __restrict__ ei, const float* __restrict__ als,
                       const float* __restrict__ ald, const float* __restrict__ m,
                       float* __restrict__ den) {
  int e = blockIdx.x * blockDim.x + threadIdx.x;
  if (e >= NETOT) return;
  int s, d;
  if (e < NE) { s = ei[e]; d = ei[NE + e]; } else { s = e - NE; d = s; }
  const float4* sv = (const float4*)(als + (size_t)s * H1N);
  const float4* dv = (const float4*)(ald + (size_t)d * H1N);
  const float4* mv = (const float4*)(m + (size_t)d * H1N);
  float4 s0 = sv[0], s1 = sv[1], d0 = dv[0], d1 = dv[1];
  float4 m0 = mv[0], m1 = mv[1];
  float* dd = den + (size_t)d * H1N;
  atomicAdd(dd + 0, expf(leakyf(s0.x + d0.x) - m0.x));
  atomicAdd(dd + 1, expf(leakyf(s0.y + d0.y) - m0.y));
  atomicAdd(dd + 2, expf(leakyf(s0.z + d0.z) - m0.z));
  atomicAdd(dd + 3, expf(leakyf(s0.w + d0.w) - m0.w));
  atomicAdd(dd + 4, expf(leakyf(s1.x + d1.x) - m1.x));
  atomicAdd(dd + 5, expf(leakyf(s1.y + d1.y) - m1.y));
  atomicAdd(dd + 6, expf(leakyf(s1.z + d1.z) - m1.z));
  atomicAdd(dd + 7, expf(leakyf(s1.w + d1.w) - m1.w));
}

// ---- layer 1 edge pass C: out[dst] += alpha * h[src], 64 lanes/edge -----
__global__ void k_agg1(const int* __restrict__ ei, const float* __restrict__ h,
                       const float* __restrict__ als, const float* __restrict__ ald,
                       const float* __restrict__ m, const float* __restrict__ den,
                       float* __restrict__ acc) {
  int t = blockIdx.x * blockDim.x + threadIdx.x;
  int e = t >> 6, c = t & 63;
  if (e >= NETOT) return;
  int s, d;
  if (e < NE) { s = ei[e]; d = ei[NE + e]; } else { s = e - NE; d = s; }
  int hd = c >> 3;
  float al = leakyf(als[(size_t)s * H1N + hd] + ald[(size_t)d * H1N + hd]);
  float a  = expf(al - m[(size_t)d * H1N + hd]) / (den[(size_t)d * H1N + hd] + 1e-16f);
  atomicAdd(&acc[(size_t)d * D1 + c], a * h[(size_t)s * D1 + c]);
}

__global__ void k_elu(float* __restrict__ v, const float* __restrict__ b, int n, int cmod) {
  int i = blockIdx.x * blockDim.x + threadIdx.x;
  if (i < n) v[i] = eluf(v[i] + b[i % cmod]);
}

// ---- layer 2: h2 = x1@W2 [N,40]; logits [N] -----------------------------
__global__ void k_lin2(const float* __restrict__ x, const float* __restrict__ W,
                       const float* __restrict__ aw_s, const float* __restrict__ aw_d,
                       float* __restrict__ h, float* __restrict__ als, float* __restrict__ ald) {
  __shared__ float xs[D1];
  int n = blockIdx.x, c = threadIdx.x;           // block = 64 threads (1 wave)
  xs[c] = x[n * D1 + c];
  __syncthreads();
  float acc = 0.0f;
  if (c < NC) {
    #pragma unroll
    for (int k = 0; k < D1; ++k) acc += xs[k] * W[k * NC + c];
    h[n * NC + c] = acc;
  }
  float s = (c < NC) ? acc * aw_s[c] : 0.0f;
  float d = (c < NC) ? acc * aw_d[c] : 0.0f;
  #pragma unroll
  for (int off = 32; off >= 1; off >>= 1) {
    s += __shfl_xor(s, off, 64);
    d += __shfl_xor(d, off, 64);
  }
  if (c == 0) { als[n] = s; ald[n] = d; }
}

__global__ void k_max2(const int* __restrict__ ei, const float* __restrict__ als,
                       const float* __restrict__ ald, float* __restrict__ m) {
  int e = blockIdx.x * blockDim.x + threadIdx.x;
  if (e >= NETOT) return;
  int s, d;
  if (e < NE) { s = ei[e]; d = ei[NE + e]; } else { s = e - NE; d = s; }
  atomicMaxF(&m[d], leakyf(als[s] + ald[d]));
}

__global__ void k_den2(const int* __restrict__ ei, const float* __restrict__ als,
                       const float* __restrict__ ald, const float* __restrict__ m,
                       float* __restrict__ den) {
  int e = blockIdx.x * blockDim.x + threadIdx.x;
  if (e >= NETOT) return;
  int s, d;
  if (e < NE) { s = ei[e]; d = ei[NE + e]; } else { s = e - NE; d = s; }
  atomicAdd(&den[d], expf(leakyf(als[s] + ald[d]) - m[d]));
}

__global__ void k_agg2(const int* __restrict__ ei, const float* __restrict__ h,
                       const float* __restrict__ als, const float* __restrict__ ald,
                       const float* __restrict__ m, const float* __restrict__ den,
                       float* __restrict__ out) {
  int t = blockIdx.x * blockDim.x + threadIdx.x;
  int e = t >> 6, c = t & 63;
  if (e >= NETOT) return;
  int s, d;
  if (e < NE) { s = ei[e]; d = ei[NE + e]; } else { s = e - NE; d = s; }
  float a = expf(leakyf(als[s] + ald[d]) - m[d]) / (den[d] + 1e-16f);
  if (c < NC) atomicAdd(&out[(size_t)d * NC + c], a * h[(size_t)s * NC + c]);
}

extern "C" void kernel_launch(void* const* d_in, const int* in_sizes, int n_in,
                              void* d_out, int out_size, void* d_ws, size_t ws_size,
                              hipStream_t stream) {
  const float* x    = (const float*)d_in[0];
  const void*  ei   = d_in[1];
  const float* W1   = (const float*)d_in[3];
  const float* as1w = (const float*)d_in[4];
  const float* ad1w = (const float*)d_in[5];
  const float* b1   = (const float*)d_in[6];
  const float* W2   = (const float*)d_in[7];
  const float* as2w = (const float*)d_in[8];
  const float* ad2w = (const float*)d_in[9];
  const float* b2   = (const float*)d_in[10];
  float* out = (float*)d_out;

  // bump-allocate workspace (layer-2 buffers reuse layer-1 buffers)
  char* w = (char*)d_ws;
  size_t off = 0;
  auto carve = [&](size_t bytes) -> void* {
    void* r = w + off;
    off += (bytes + 255) & ~(size_t)255;
    return r;
  };
  int*   ei32 = (int*)carve((size_t)2 * NE * 4);
  int*   flag = (int*)carve(256);
  float* h1   = (float*)carve((size_t)NN * D1 * 4);   // reused as h2
  float* as1  = (float*)carve((size_t)NN * H1N * 4);  // reused as as2
  float* ad1  = (float*)carve((size_t)NN * H1N * 4);  // reused as ad2
  float* m1   = (float*)carve((size_t)NN * H1N * 4);  // reused as m2
  float* den1 = (float*)carve((size_t)NN * H1N * 4);  // reused as den2
  float* acc1 = (float*)carve((size_t)NN * D1 * 4);   // x1 after ELU
  float* h2 = h1; float* as2 = as1; float* ad2 = ad1; float* m2 = m1; float* den2 = den1;

  const int EB  = (NETOT + 255) / 256;                 // edge-parallel blocks
  const int AB  = ((NETOT * 64) + 255) / 256;          // (edge,lane64) blocks

  // edge-index normalize
  k_detect<<<1, 64, 0, stream>>>((const long long*)ei, flag);
  k_convert<<<(2 * NE + 255) / 256, 256, 0, stream>>>(ei, flag, ei32, 2 * NE);

  // ---- layer 1 ----
  hipMemsetAsync(den1, 0, (size_t)NN * H1N * 4, stream);
  hipMemsetAsync(acc1, 0, (size_t)NN * D1 * 4, stream);
  k_neginf<<<(NN * H1N + 255) / 256, 256, 0, stream>>>(m1, NN * H1N);
  k_lin1<<<NN, 64, 0, stream>>>(x, W1, as1w, ad1w, h1, as1, ad1);
  k_max1<<<EB, 256, 0, stream>>>(ei32, as1, ad1, m1);
  k_den1<<<EB, 256, 0, stream>>>(ei32, as1, ad1, m1, den1);
  k_agg1<<<AB, 256, 0, stream>>>(ei32, h1, as1, ad1, m1, den1, acc1);
  k_elu<<<(NN * D1 + 255) / 256, 256, 0, stream>>>(acc1, b1, NN * D1, D1);

  // ---- layer 2 (buffers reused; inits re-enqueued in stream order) ----
  hipMemsetAsync(den2, 0, (size_t)NN * 4, stream);
  hipMemsetAsync(out, 0, (size_t)NN * NC * 4, stream);
  k_neginf<<<(NN + 255) / 256, 256, 0, stream>>>(m2, NN);
  k_lin2<<<NN, 64, 0, stream>>>(acc1, W2, as2w, ad2w, h2, as2, ad2);
  k_max2<<<EB, 256, 0, stream>>>(ei32, as2, ad2, m2);
  k_den2<<<EB, 256, 0, stream>>>(ei32, as2, ad2, m2, den2);
  k_agg2<<<AB, 256, 0, stream>>>(ei32, h2, as2, ad2, m2, den2, out);
  k_elu<<<(NN * NC + 255) / 256, 256, 0, stream>>>(out, b2, NN * NC, NC);
}

// Round 2
// 782.394 us; speedup vs baseline: 2.8865x; 2.8865x over previous
//
#include <hip/hip_runtime.h>
#include <math.h>

#define NN 100000
#define NE 1600000
#define NETOT (NE + NN)
#define FIN 128
#define H1N 8
#define D1 64
#define NC 40
#define NB_SCAN ((NN + 255) / 256)   // 391

__device__ __forceinline__ float leakyf(float x) { return x >= 0.0f ? x : 0.2f * x; }
__device__ __forceinline__ float eluf(float x)   { return x > 0.0f ? x : expm1f(x); }

// ---- edge_index dtype detection (int64 vs int32) ------------------------
__global__ void k_detect(const long long* __restrict__ ei, int* __restrict__ flag) {
  if (blockIdx.x == 0 && threadIdx.x == 0) {
    int is64 = 1;
    for (int i = 0; i < 16; ++i) {
      long long v = ei[i];
      if (v < 0 || v >= NN) is64 = 0;
    }
    *flag = is64;
  }
}

__global__ void k_convert(const void* __restrict__ ei, const int* __restrict__ flag,
                          int* __restrict__ o, int n) {
  int i = blockIdx.x * blockDim.x + threadIdx.x;
  if (i >= n) return;
  o[i] = (*flag) ? (int)((const long long*)ei)[i] : ((const int*)ei)[i];
}

// ---- CSR build: histogram -> scan -> scatter -----------------------------
__global__ void k_hist(const int* __restrict__ ei, int* __restrict__ deg) {
  int e = blockIdx.x * blockDim.x + threadIdx.x;
  if (e >= NETOT) return;
  int d = (e < NE) ? ei[NE + e] : (e - NE);
  atomicAdd(&deg[d], 1);
}

__global__ void k_chunksum(const int* __restrict__ deg, int* __restrict__ bsum) {
  __shared__ int sh[256];
  int t = threadIdx.x, i = blockIdx.x * 256 + t;
  sh[t] = (i < NN) ? deg[i] : 0;
  __syncthreads();
  for (int s = 128; s > 0; s >>= 1) { if (t < s) sh[t] += sh[t + s]; __syncthreads(); }
  if (t == 0) bsum[blockIdx.x] = sh[0];
}

__global__ void k_scanbsum(const int* __restrict__ bsum, int* __restrict__ boff) {
  if (threadIdx.x == 0 && blockIdx.x == 0) {
    int acc = 0;
    for (int i = 0; i < NB_SCAN; ++i) { boff[i] = acc; acc += bsum[i]; }
    boff[NB_SCAN] = acc;
  }
}

__global__ void k_scanfinal(const int* __restrict__ deg, const int* __restrict__ boff,
                            int* __restrict__ row_start, int* __restrict__ cursor) {
  __shared__ int sh[256];
  int t = threadIdx.x, b = blockIdx.x, i = b * 256 + t;
  int v = (i < NN) ? deg[i] : 0;
  sh[t] = v;
  __syncthreads();
  for (int s = 1; s < 256; s <<= 1) {
    int x = (t >= s) ? sh[t - s] : 0;
    __syncthreads();
    sh[t] += x;
    __syncthreads();
  }
  if (i < NN) {
    int excl = boff[b] + sh[t] - v;
    row_start[i] = excl;
    cursor[i] = excl;
    if (i == NN - 1) row_start[NN] = excl + v;
  }
}

__global__ void k_scatter(const int* __restrict__ ei, int* __restrict__ cursor,
                          int* __restrict__ csr) {
  int e = blockIdx.x * blockDim.x + threadIdx.x;
  if (e >= NETOT) return;
  int s, d;
  if (e < NE) { s = ei[e]; d = ei[NE + e]; } else { s = e - NE; d = s; }
  int pos = atomicAdd(&cursor[d], 1);
  csr[pos] = s;
}

// ---- layer 1: h1 = x@W1 [N,64]; per-node attention logits [N,8] ---------
__global__ void k_lin1(const float* __restrict__ x, const float* __restrict__ W,
                       const float* __restrict__ aw_s, const float* __restrict__ aw_d,
                       float* __restrict__ h, float* __restrict__ als, float* __restrict__ ald) {
  __shared__ float xs[FIN];
  int n = blockIdx.x, c = threadIdx.x;           // block = 64 threads (1 wave)
  xs[c]      = x[n * FIN + c];
  xs[c + 64] = x[n * FIN + 64 + c];
  __syncthreads();
  float acc = 0.0f;
  #pragma unroll
  for (int k = 0; k < FIN; ++k) acc += xs[k] * W[k * D1 + c];
  h[(size_t)n * D1 + c] = acc;
  int head = c >> 3, cc = c & 7;
  float s = acc * aw_s[c];
  float d = acc * aw_d[c];
  #pragma unroll
  for (int off = 4; off >= 1; off >>= 1) {
    s += __shfl_xor(s, off);
    d += __shfl_xor(d, off);
  }
  if (cc == 0) { als[n * H1N + head] = s; ald[n * H1N + head] = d; }
}

// ---- layer 1 fused per-node softmax + aggregate + bias + ELU ------------
// one wave per node; lanes as (eo=lane>>3, hd=lane&7) for max/den, channel for agg
__global__ void k_node1(const int* __restrict__ row_start, const int* __restrict__ csr,
                        const float* __restrict__ h, const float* __restrict__ als,
                        const float* __restrict__ ald, const float* __restrict__ b,
                        float* __restrict__ x1) {
  int wid = threadIdx.x >> 6, lane = threadIdx.x & 63;
  int n = blockIdx.x * (blockDim.x >> 6) + wid;
  if (n >= NN) return;
  int r0 = row_start[n], deg = row_start[n + 1] - r0;
  int eo = lane >> 3, hd = lane & 7;
  float aldv = ald[n * H1N + hd];
  // pass A: per-head max over in-edges
  float M = -INFINITY;
  for (int k = eo; k < deg; k += 8) {
    int s = csr[r0 + k];
    M = fmaxf(M, leakyf(als[s * H1N + hd] + aldv));
  }
  M = fmaxf(M, __shfl_xor(M, 8));
  M = fmaxf(M, __shfl_xor(M, 16));
  M = fmaxf(M, __shfl_xor(M, 32));
  // pass B: per-head denom
  float S = 0.0f;
  for (int k = eo; k < deg; k += 8) {
    int s = csr[r0 + k];
    S += expf(leakyf(als[s * H1N + hd] + aldv) - M);
  }
  S += __shfl_xor(S, 8);
  S += __shfl_xor(S, 16);
  S += __shfl_xor(S, 32);
  // remap to channel layout: lane c owns channel c, head hd2=c>>3 (values live in lanes 0..7)
  int hd2 = lane >> 3;
  float Mc   = __shfl(M, hd2);
  float Sc   = __shfl(S, hd2);
  float aldc = __shfl(aldv, hd2);
  float inv = 1.0f / (Sc + 1e-16f);
  // pass C: weighted aggregate, lane = channel
  float acc = 0.0f;
  for (int k = 0; k < deg; ++k) {
    int s = csr[r0 + k];
    float a = expf(leakyf(als[s * H1N + hd2] + aldc) - Mc) * inv;
    acc += a * h[(size_t)s * D1 + lane];
  }
  x1[(size_t)n * D1 + lane] = eluf(acc + b[lane]);
}

// ---- layer 2: h2 = x1@W2 [N,40]; scalar logits [N] -----------------------
__global__ void k_lin2(const float* __restrict__ x, const float* __restrict__ W,
                       const float* __restrict__ aw_s, const float* __restrict__ aw_d,
                       float* __restrict__ h, float* __restrict__ als, float* __restrict__ ald) {
  __shared__ float xs[D1];
  int n = blockIdx.x, c = threadIdx.x;           // block = 64 threads (1 wave)
  xs[c] = x[(size_t)n * D1 + c];
  __syncthreads();
  float acc = 0.0f;
  if (c < NC) {
    #pragma unroll
    for (int k = 0; k < D1; ++k) acc += xs[k] * W[k * NC + c];
    h[(size_t)n * NC + c] = acc;
  }
  float s = (c < NC) ? acc * aw_s[c] : 0.0f;
  float d = (c < NC) ? acc * aw_d[c] : 0.0f;
  #pragma unroll
  for (int off = 32; off >= 1; off >>= 1) {
    s += __shfl_xor(s, off);
    d += __shfl_xor(d, off);
  }
  if (c == 0) { als[n] = s; ald[n] = d; }
}

// ---- layer 2 fused per-node softmax + aggregate + bias + ELU ------------
__global__ void k_node2(const int* __restrict__ row_start, const int* __restrict__ csr,
                        const float* __restrict__ h, const float* __restrict__ als,
                        const float* __restrict__ ald, const float* __restrict__ b,
                        float* __restrict__ out) {
  int wid = threadIdx.x >> 6, lane = threadIdx.x & 63;
  int n = blockIdx.x * (blockDim.x >> 6) + wid;
  if (n >= NN) return;
  int r0 = row_start[n], deg = row_start[n + 1] - r0;
  float aldn = ald[n];
  // pass A: max (lane-strided over edges)
  float M = -INFINITY;
  for (int k = lane; k < deg; k += 64) {
    int s = csr[r0 + k];
    M = fmaxf(M, leakyf(als[s] + aldn));
  }
  #pragma unroll
  for (int off = 32; off >= 1; off >>= 1) M = fmaxf(M, __shfl_xor(M, off));
  // pass B: denom
  float S = 0.0f;
  for (int k = lane; k < deg; k += 64) {
    int s = csr[r0 + k];
    S += expf(leakyf(als[s] + aldn) - M);
  }
  #pragma unroll
  for (int off = 32; off >= 1; off >>= 1) S += __shfl_xor(S, off);
  float inv = 1.0f / (S + 1e-16f);
  // pass C: aggregate, lane = channel (first 40 lanes)
  float acc = 0.0f;
  for (int k = 0; k < deg; ++k) {
    int s = csr[r0 + k];
    float a = expf(leakyf(als[s] + aldn) - M) * inv;
    if (lane < NC) acc += a * h[(size_t)s * NC + lane];
  }
  if (lane < NC) out[(size_t)n * NC + lane] = eluf(acc + b[lane]);
}

extern "C" void kernel_launch(void* const* d_in, const int* in_sizes, int n_in,
                              void* d_out, int out_size, void* d_ws, size_t ws_size,
                              hipStream_t stream) {
  const float* x    = (const float*)d_in[0];
  const void*  ei   = d_in[1];
  const float* W1   = (const float*)d_in[3];
  const float* as1w = (const float*)d_in[4];
  const float* ad1w = (const float*)d_in[5];
  const float* b1   = (const float*)d_in[6];
  const float* W2   = (const float*)d_in[7];
  const float* as2w = (const float*)d_in[8];
  const float* ad2w = (const float*)d_in[9];
  const float* b2   = (const float*)d_in[10];
  float* out = (float*)d_out;

  char* w = (char*)d_ws;
  size_t off = 0;
  auto carve = [&](size_t bytes) -> void* {
    void* r = w + off;
    off += (bytes + 255) & ~(size_t)255;
    return r;
  };
  int*   ei32      = (int*)carve((size_t)2 * NE * 4);
  int*   flag      = (int*)carve(256);
  int*   deg       = (int*)carve((size_t)NN * 4);
  int*   row_start = (int*)carve((size_t)(NN + 1) * 4);
  int*   cursor    = (int*)carve((size_t)NN * 4);
  int*   bsum      = (int*)carve((size_t)NB_SCAN * 4);
  int*   boff      = (int*)carve((size_t)(NB_SCAN + 1) * 4);
  int*   csr       = (int*)carve((size_t)NETOT * 4);
  float* h1        = (float*)carve((size_t)NN * D1 * 4);   // reused as h2 [N,40]
  float* als1      = (float*)carve((size_t)NN * H1N * 4);  // reused as als2 [N]
  float* ald1      = (float*)carve((size_t)NN * H1N * 4);  // reused as ald2 [N]
  float* x1        = (float*)carve((size_t)NN * D1 * 4);
  float* h2 = h1; float* als2 = als1; float* ald2 = ald1;

  const int EB = (NETOT + 255) / 256;

  // edge-index normalize
  k_detect<<<1, 64, 0, stream>>>((const long long*)ei, flag);
  k_convert<<<(2 * NE + 255) / 256, 256, 0, stream>>>(ei, flag, ei32, 2 * NE);

  // CSR build (by dst), self-loops included
  hipMemsetAsync(deg, 0, (size_t)NN * 4, stream);
  k_hist<<<EB, 256, 0, stream>>>(ei32, deg);
  k_chunksum<<<NB_SCAN, 256, 0, stream>>>(deg, bsum);
  k_scanbsum<<<1, 64, 0, stream>>>(bsum, boff);
  k_scanfinal<<<NB_SCAN, 256, 0, stream>>>(deg, boff, row_start, cursor);
  k_scatter<<<EB, 256, 0, stream>>>(ei32, cursor, csr);

  // layer 1
  k_lin1<<<NN, 64, 0, stream>>>(x, W1, as1w, ad1w, h1, als1, ald1);
  k_node1<<<NN / 4, 256, 0, stream>>>(row_start, csr, h1, als1, ald1, b1, x1);

  // layer 2
  k_lin2<<<NN, 64, 0, stream>>>(x1, W2, as2w, ad2w, h2, als2, ald2);
  k_node2<<<NN / 4, 256, 0, stream>>>(row_start, csr, h2, als2, ald2, b2, out);
}

// Round 3
// 781.666 us; speedup vs baseline: 2.8891x; 1.0009x over previous
//
#include <hip/hip_runtime.h>
#include <math.h>

#define NN 100000
#define NE 1600000
#define NETOT (NE + NN)
#define FIN 128
#define H1N 8
#define D1 64
#define NC 40
#define NB_SCAN ((NN + 255) / 256)   // 391
#define NPB 16                        // nodes per block in lin kernels

__device__ __forceinline__ float leakyf(float x) { return x >= 0.0f ? x : 0.2f * x; }
__device__ __forceinline__ float eluf(float x)   { return x > 0.0f ? x : expm1f(x); }

// ---- edge_index dtype detection (int64 vs int32) ------------------------
__global__ void k_detect(const long long* __restrict__ ei, int* __restrict__ flag) {
  if (blockIdx.x == 0 && threadIdx.x == 0) {
    int is64 = 1;
    for (int i = 0; i < 16; ++i) {
      long long v = ei[i];
      if (v < 0 || v >= NN) is64 = 0;
    }
    *flag = is64;
  }
}

__global__ void k_convert(const void* __restrict__ ei, const int* __restrict__ flag,
                          int* __restrict__ o, int n) {
  int i = blockIdx.x * blockDim.x + threadIdx.x;
  if (i >= n) return;
  o[i] = (*flag) ? (int)((const long long*)ei)[i] : ((const int*)ei)[i];
}

// ---- CSR build: histogram -> scan -> scatter -----------------------------
__global__ void k_deginit(int* __restrict__ deg) {       // self-loop pre-counted
  int i = blockIdx.x * blockDim.x + threadIdx.x;
  if (i < NN) deg[i] = 1;
}

__global__ void k_hist(const int* __restrict__ ei, int* __restrict__ deg) {
  int e = blockIdx.x * blockDim.x + threadIdx.x;
  if (e < NE) atomicAdd(&deg[ei[NE + e]], 1);
}

__global__ void k_chunksum(const int* __restrict__ deg, int* __restrict__ bsum) {
  __shared__ int sh[256];
  int t = threadIdx.x, i = blockIdx.x * 256 + t;
  sh[t] = (i < NN) ? deg[i] : 0;
  __syncthreads();
  for (int s = 128; s > 0; s >>= 1) { if (t < s) sh[t] += sh[t + s]; __syncthreads(); }
  if (t == 0) bsum[blockIdx.x] = sh[0];
}

// one-block parallel scan of the 391 block sums (replaces serial loop)
__global__ void k_scanbsum(const int* __restrict__ bsum, int* __restrict__ boff) {
  __shared__ int sh[512];
  int t = threadIdx.x;
  int v = (t < NB_SCAN) ? bsum[t] : 0;
  sh[t] = v;
  __syncthreads();
  for (int s = 1; s < 512; s <<= 1) {
    int x = (t >= s) ? sh[t - s] : 0;
    __syncthreads();
    sh[t] += x;
    __syncthreads();
  }
  if (t < NB_SCAN) boff[t] = sh[t] - v;
  if (t == NB_SCAN - 1) boff[NB_SCAN] = sh[t];
}

__global__ void k_scanfinal(const int* __restrict__ deg, const int* __restrict__ boff,
                            int* __restrict__ row_start, int* __restrict__ cursor,
                            int* __restrict__ csr) {
  __shared__ int sh[256];
  int t = threadIdx.x, b = blockIdx.x, i = b * 256 + t;
  int v = (i < NN) ? deg[i] : 0;
  sh[t] = v;
  __syncthreads();
  for (int s = 1; s < 256; s <<= 1) {
    int x = (t >= s) ? sh[t - s] : 0;
    __syncthreads();
    sh[t] += x;
    __syncthreads();
  }
  if (i < NN) {
    int excl = boff[b] + sh[t] - v;
    row_start[i] = excl;
    csr[excl] = i;            // self-loop pre-placed
    cursor[i] = excl + 1;
    if (i == NN - 1) row_start[NN] = excl + v;
  }
}

__global__ void k_scatter(const int* __restrict__ ei, int* __restrict__ cursor,
                          int* __restrict__ csr) {
  int e = blockIdx.x * blockDim.x + threadIdx.x;
  if (e >= NE) return;
  int s = ei[e], d = ei[NE + e];
  int pos = atomicAdd(&cursor[d], 1);
  csr[pos] = s;
}

// ---- layer 1 linear: h1 = x@W1 [N,64]; logits [N,8] ----------------------
// block = 64 (1 wave); W1 column held in 128 VGPRs; x row loads are wave-uniform
__global__ void k_lin1(const float* __restrict__ x, const float* __restrict__ W,
                       const float* __restrict__ aw_s, const float* __restrict__ aw_d,
                       float* __restrict__ h, float* __restrict__ als, float* __restrict__ ald) {
  int lane = threadIdx.x;
  float wcol[FIN];
  #pragma unroll
  for (int k = 0; k < FIN; ++k) wcol[k] = W[k * D1 + lane];
  float ws = aw_s[lane], wd = aw_d[lane];
  int n0 = blockIdx.x * NPB;
  for (int i = 0; i < NPB; ++i) {
    int n = n0 + i;
    if (n >= NN) return;
    const float* __restrict__ xr = x + (size_t)n * FIN;
    float a0 = 0.f, a1 = 0.f, a2 = 0.f, a3 = 0.f;
    #pragma unroll
    for (int k = 0; k < FIN; k += 4) {
      a0 = fmaf(xr[k + 0], wcol[k + 0], a0);
      a1 = fmaf(xr[k + 1], wcol[k + 1], a1);
      a2 = fmaf(xr[k + 2], wcol[k + 2], a2);
      a3 = fmaf(xr[k + 3], wcol[k + 3], a3);
    }
    float acc = (a0 + a1) + (a2 + a3);
    h[(size_t)n * D1 + lane] = acc;
    float s = acc * ws, d = acc * wd;
    s += __shfl_xor(s, 1); d += __shfl_xor(d, 1);
    s += __shfl_xor(s, 2); d += __shfl_xor(d, 2);
    s += __shfl_xor(s, 4); d += __shfl_xor(d, 4);
    if ((lane & 7) == 0) {
      als[n * H1N + (lane >> 3)] = s;
      ald[n * H1N + (lane >> 3)] = d;
    }
  }
}

// ---- layer 1 fused single-pass aggregate (softmax shift-invariance) ------
// one wave per node, lane = output channel, head = lane>>3
__global__ void k_node1(const int* __restrict__ row_start, const int* __restrict__ csr,
                        const float* __restrict__ h, const float* __restrict__ als,
                        const float* __restrict__ ald, const float* __restrict__ b,
                        float* __restrict__ x1) {
  int wid = threadIdx.x >> 6, lane = threadIdx.x & 63;
  int n = blockIdx.x * 4 + wid;
  if (n >= NN) return;
  int r0 = row_start[n], r1 = row_start[n + 1];
  int hd = lane >> 3;
  float aldv = ald[n * H1N + hd];
  float S = 0.f, acc = 0.f;
  for (int k = r0; k < r1; ++k) {
    int s = csr[k];
    float p = __expf(leakyf(als[s * H1N + hd] + aldv));
    S += p;
    acc = fmaf(p, h[(size_t)s * D1 + lane], acc);
  }
  x1[(size_t)n * D1 + lane] = eluf(acc / (S + 1e-16f) + b[lane]);
}

// ---- layer 2 linear: h2 = x1@W2 [N,40]; scalar logits [N] -----------------
__global__ void k_lin2(const float* __restrict__ x, const float* __restrict__ W,
                       const float* __restrict__ aw_s, const float* __restrict__ aw_d,
                       float* __restrict__ h, float* __restrict__ als, float* __restrict__ ald) {
  int lane = threadIdx.x;
  int cl = lane < NC ? lane : NC - 1;          // clamp to stay in-bounds
  float wcol[D1];
  #pragma unroll
  for (int k = 0; k < D1; ++k) wcol[k] = W[k * NC + cl];
  float ws = aw_s[cl], wd = aw_d[cl];
  int n0 = blockIdx.x * NPB;
  for (int i = 0; i < NPB; ++i) {
    int n = n0 + i;
    if (n >= NN) return;
    const float* __restrict__ xr = x + (size_t)n * D1;
    float a0 = 0.f, a1 = 0.f, a2 = 0.f, a3 = 0.f;
    #pragma unroll
    for (int k = 0; k < D1; k += 4) {
      a0 = fmaf(xr[k + 0], wcol[k + 0], a0);
      a1 = fmaf(xr[k + 1], wcol[k + 1], a1);
      a2 = fmaf(xr[k + 2], wcol[k + 2], a2);
      a3 = fmaf(xr[k + 3], wcol[k + 3], a3);
    }
    float acc = (a0 + a1) + (a2 + a3);
    if (lane < NC) h[(size_t)n * NC + lane] = acc;
    float s = (lane < NC) ? acc * ws : 0.f;
    float d = (lane < NC) ? acc * wd : 0.f;
    #pragma unroll
    for (int off = 32; off >= 1; off >>= 1) {
      s += __shfl_xor(s, off);
      d += __shfl_xor(d, off);
    }
    if (lane == 0) { als[n] = s; ald[n] = d; }
  }
}

// ---- layer 2 fused single-pass aggregate ---------------------------------
__global__ void k_node2(const int* __restrict__ row_start, const int* __restrict__ csr,
                        const float* __restrict__ h, const float* __restrict__ als,
                        const float* __restrict__ ald, const float* __restrict__ b,
                        float* __restrict__ out) {
  int wid = threadIdx.x >> 6, lane = threadIdx.x & 63;
  int n = blockIdx.x * 4 + wid;
  if (n >= NN) return;
  int r0 = row_start[n], r1 = row_start[n + 1];
  float aldv = ald[n];
  float S = 0.f, acc = 0.f;
  for (int k = r0; k < r1; ++k) {
    int s = csr[k];
    float p = __expf(leakyf(als[s] + aldv));
    S += p;
    if (lane < NC) acc = fmaf(p, h[(size_t)s * NC + lane], acc);
  }
  if (lane < NC) out[(size_t)n * NC + lane] = eluf(acc / (S + 1e-16f) + b[lane]);
}

extern "C" void kernel_launch(void* const* d_in, const int* in_sizes, int n_in,
                              void* d_out, int out_size, void* d_ws, size_t ws_size,
                              hipStream_t stream) {
  const float* x    = (const float*)d_in[0];
  const void*  ei   = d_in[1];
  const float* W1   = (const float*)d_in[3];
  const float* as1w = (const float*)d_in[4];
  const float* ad1w = (const float*)d_in[5];
  const float* b1   = (const float*)d_in[6];
  const float* W2   = (const float*)d_in[7];
  const float* as2w = (const float*)d_in[8];
  const float* ad2w = (const float*)d_in[9];
  const float* b2   = (const float*)d_in[10];
  float* out = (float*)d_out;

  char* w = (char*)d_ws;
  size_t off = 0;
  auto carve = [&](size_t bytes) -> void* {
    void* r = w + off;
    off += (bytes + 255) & ~(size_t)255;
    return r;
  };
  int*   ei32      = (int*)carve((size_t)2 * NE * 4);
  int*   flag      = (int*)carve(256);
  int*   deg       = (int*)carve((size_t)NN * 4);
  int*   row_start = (int*)carve((size_t)(NN + 1) * 4);
  int*   cursor    = (int*)carve((size_t)NN * 4);
  int*   bsum      = (int*)carve((size_t)NB_SCAN * 4);
  int*   boff      = (int*)carve((size_t)(NB_SCAN + 1) * 4);
  int*   csr       = (int*)carve((size_t)NETOT * 4);
  float* h1        = (float*)carve((size_t)NN * D1 * 4);   // reused as h2 [N,40]
  float* als1      = (float*)carve((size_t)NN * H1N * 4);  // reused as als2 [N]
  float* ald1      = (float*)carve((size_t)NN * H1N * 4);  // reused as ald2 [N]
  float* x1        = (float*)carve((size_t)NN * D1 * 4);
  float* h2 = h1; float* als2 = als1; float* ald2 = ald1;

  const int EB  = (NE + 255) / 256;
  const int LB  = (NN + NPB - 1) / NPB;

  // edge-index normalize
  k_detect<<<1, 64, 0, stream>>>((const long long*)ei, flag);
  k_convert<<<(2 * NE + 255) / 256, 256, 0, stream>>>(ei, flag, ei32, 2 * NE);

  // CSR build (by dst), self-loops pre-placed
  k_deginit<<<(NN + 255) / 256, 256, 0, stream>>>(deg);
  k_hist<<<EB, 256, 0, stream>>>(ei32, deg);
  k_chunksum<<<NB_SCAN, 256, 0, stream>>>(deg, bsum);
  k_scanbsum<<<1, 512, 0, stream>>>(bsum, boff);
  k_scanfinal<<<NB_SCAN, 256, 0, stream>>>(deg, boff, row_start, cursor, csr);
  k_scatter<<<EB, 256, 0, stream>>>(ei32, cursor, csr);

  // layer 1
  k_lin1<<<LB, 64, 0, stream>>>(x, W1, as1w, ad1w, h1, als1, ald1);
  k_node1<<<NN / 4, 256, 0, stream>>>(row_start, csr, h1, als1, ald1, b1, x1);

  // layer 2
  k_lin2<<<LB, 64, 0, stream>>>(x1, W2, as2w, ad2w, h2, als2, ald2);
  k_node2<<<NN / 4, 256, 0, stream>>>(row_start, csr, h2, als2, ald2, b2, out);
}

// Round 4
// 534.271 us; speedup vs baseline: 4.2270x; 1.4631x over previous
//
#include <hip/hip_runtime.h>
#include <math.h>

#define NN 100000
#define NE 1600000
#define NETOT (NE + NN)
#define FIN 128
#define H1N 8
#define D1 64
#define NC 40
#define NB_SCAN ((NN + 255) / 256)   // 391
#define NPB 16                        // nodes per block in lin kernels

__device__ __forceinline__ float leakyf(float x) { return x >= 0.0f ? x : 0.2f * x; }
__device__ __forceinline__ float eluf(float x)   { return x > 0.0f ? x : expm1f(x); }

// ---- edge_index dtype detection (int64 vs int32) ------------------------
__global__ void k_detect(const long long* __restrict__ ei, int* __restrict__ flag) {
  if (blockIdx.x == 0 && threadIdx.x == 0) {
    int is64 = 1;
    for (int i = 0; i < 16; ++i) {
      long long v = ei[i];
      if (v < 0 || v >= NN) is64 = 0;
    }
    *flag = is64;
  }
}

__global__ void k_convert(const void* __restrict__ ei, const int* __restrict__ flag,
                          int* __restrict__ o, int n) {
  int i = blockIdx.x * blockDim.x + threadIdx.x;
  if (i >= n) return;
  o[i] = (*flag) ? (int)((const long long*)ei)[i] : ((const int*)ei)[i];
}

// ---- CSR build: histogram -> scan -> scatter -----------------------------
__global__ void k_deginit(int* __restrict__ deg) {       // self-loop pre-counted
  int i = blockIdx.x * blockDim.x + threadIdx.x;
  if (i < NN) deg[i] = 1;
}

__global__ void k_hist(const int* __restrict__ ei, int* __restrict__ deg) {
  int e = blockIdx.x * blockDim.x + threadIdx.x;
  if (e < NE) atomicAdd(&deg[ei[NE + e]], 1);
}

__global__ void k_chunksum(const int* __restrict__ deg, int* __restrict__ bsum) {
  __shared__ int sh[256];
  int t = threadIdx.x, i = blockIdx.x * 256 + t;
  sh[t] = (i < NN) ? deg[i] : 0;
  __syncthreads();
  for (int s = 128; s > 0; s >>= 1) { if (t < s) sh[t] += sh[t + s]; __syncthreads(); }
  if (t == 0) bsum[blockIdx.x] = sh[0];
}

__global__ void k_scanbsum(const int* __restrict__ bsum, int* __restrict__ boff) {
  __shared__ int sh[512];
  int t = threadIdx.x;
  int v = (t < NB_SCAN) ? bsum[t] : 0;
  sh[t] = v;
  __syncthreads();
  for (int s = 1; s < 512; s <<= 1) {
    int x = (t >= s) ? sh[t - s] : 0;
    __syncthreads();
    sh[t] += x;
    __syncthreads();
  }
  if (t < NB_SCAN) boff[t] = sh[t] - v;
  if (t == NB_SCAN - 1) boff[NB_SCAN] = sh[t];
}

__global__ void k_scanfinal(const int* __restrict__ deg, const int* __restrict__ boff,
                            int* __restrict__ row_start, int* __restrict__ cursor,
                            int* __restrict__ csr) {
  __shared__ int sh[256];
  int t = threadIdx.x, b = blockIdx.x, i = b * 256 + t;
  int v = (i < NN) ? deg[i] : 0;
  sh[t] = v;
  __syncthreads();
  for (int s = 1; s < 256; s <<= 1) {
    int x = (t >= s) ? sh[t - s] : 0;
    __syncthreads();
    sh[t] += x;
    __syncthreads();
  }
  if (i < NN) {
    int excl = boff[b] + sh[t] - v;
    row_start[i] = excl;
    csr[excl] = i;            // self-loop pre-placed
    cursor[i] = excl + 1;
    if (i == NN - 1) row_start[NN] = excl + v;
  }
}

__global__ void k_scatter(const int* __restrict__ ei, int* __restrict__ cursor,
                          int* __restrict__ csr) {
  int e = blockIdx.x * blockDim.x + threadIdx.x;
  if (e >= NE) return;
  int s = ei[e], d = ei[NE + e];
  int pos = atomicAdd(&cursor[d], 1);
  csr[pos] = s;
}

// ---- layer 1 linear: h1 = x@W1 [N,64]; logits [N,8] ----------------------
__global__ void k_lin1(const float* __restrict__ x, const float* __restrict__ W,
                       const float* __restrict__ aw_s, const float* __restrict__ aw_d,
                       float* __restrict__ h, float* __restrict__ als, float* __restrict__ ald) {
  int lane = threadIdx.x;
  float wcol[FIN];
  #pragma unroll
  for (int k = 0; k < FIN; ++k) wcol[k] = W[k * D1 + lane];
  float ws = aw_s[lane], wd = aw_d[lane];
  int n0 = blockIdx.x * NPB;
  for (int i = 0; i < NPB; ++i) {
    int n = n0 + i;
    if (n >= NN) return;
    const float* __restrict__ xr = x + (size_t)n * FIN;
    float a0 = 0.f, a1 = 0.f, a2 = 0.f, a3 = 0.f;
    #pragma unroll
    for (int k = 0; k < FIN; k += 4) {
      a0 = fmaf(xr[k + 0], wcol[k + 0], a0);
      a1 = fmaf(xr[k + 1], wcol[k + 1], a1);
      a2 = fmaf(xr[k + 2], wcol[k + 2], a2);
      a3 = fmaf(xr[k + 3], wcol[k + 3], a3);
    }
    float acc = (a0 + a1) + (a2 + a3);
    h[(size_t)n * D1 + lane] = acc;
    float s = acc * ws, d = acc * wd;
    s += __shfl_xor(s, 1); d += __shfl_xor(d, 1);
    s += __shfl_xor(s, 2); d += __shfl_xor(d, 2);
    s += __shfl_xor(s, 4); d += __shfl_xor(d, 4);
    if ((lane & 7) == 0) {
      als[n * H1N + (lane >> 3)] = s;
      ald[n * H1N + (lane >> 3)] = d;
    }
  }
}

// ---- layer 1 fused single-pass aggregate, chunked wave-parallel ----------
// one wave per node. Per 64-edge chunk: (A) coalesced csr load (lane=edge),
// (B) lane-parallel als-row gather + 8 exps -> LDS p[edge][head] (stride 9,
// conflict-free; slot 8 carries src idx), (C) channel-aggregate with 4-way
// unrolled h-row gathers (4 independent 256B gathers in flight per stall).
__global__ void k_node1(const int* __restrict__ row_start, const int* __restrict__ csr,
                        const float* __restrict__ h, const float* __restrict__ als,
                        const float* __restrict__ ald, const float* __restrict__ b,
                        float* __restrict__ x1) {
  __shared__ float pl[4][64 * 9];
  int wid = threadIdx.x >> 6, lane = threadIdx.x & 63;
  int n = blockIdx.x * 4 + wid;
  if (n >= NN) return;
  float* pw = pl[wid];
  int r0 = row_start[n], r1 = row_start[n + 1];
  int hd = lane >> 3;
  const float4* adp = (const float4*)(ald + (size_t)n * H1N);
  float4 ad0 = adp[0], ad1 = adp[1];
  float S = 0.f, acc0 = 0.f, acc1 = 0.f, acc2 = 0.f, acc3 = 0.f;
  for (int kb = r0; kb < r1; kb += 64) {
    int cnt = min(64, r1 - kb);
    if (lane < cnt) {
      int sk = csr[kb + lane];
      const float4* ap = (const float4*)(als + (size_t)sk * H1N);
      float4 a0 = ap[0], a1 = ap[1];
      pw[lane * 9 + 0] = __expf(leakyf(a0.x + ad0.x));
      pw[lane * 9 + 1] = __expf(leakyf(a0.y + ad0.y));
      pw[lane * 9 + 2] = __expf(leakyf(a0.z + ad0.z));
      pw[lane * 9 + 3] = __expf(leakyf(a0.w + ad0.w));
      pw[lane * 9 + 4] = __expf(leakyf(a1.x + ad1.x));
      pw[lane * 9 + 5] = __expf(leakyf(a1.y + ad1.y));
      pw[lane * 9 + 6] = __expf(leakyf(a1.z + ad1.z));
      pw[lane * 9 + 7] = __expf(leakyf(a1.w + ad1.w));
      pw[lane * 9 + 8] = __int_as_float(sk);
    }
    asm volatile("s_waitcnt lgkmcnt(0)" ::: "memory");   // wave-internal LDS RAW
    int j = 0;
    for (; j + 4 <= cnt; j += 4) {
      int s0 = __float_as_int(pw[(j + 0) * 9 + 8]);
      int s1 = __float_as_int(pw[(j + 1) * 9 + 8]);
      int s2 = __float_as_int(pw[(j + 2) * 9 + 8]);
      int s3 = __float_as_int(pw[(j + 3) * 9 + 8]);
      float p0 = pw[(j + 0) * 9 + hd], p1 = pw[(j + 1) * 9 + hd];
      float p2 = pw[(j + 2) * 9 + hd], p3 = pw[(j + 3) * 9 + hd];
      float g0 = h[(size_t)s0 * D1 + lane];
      float g1 = h[(size_t)s1 * D1 + lane];
      float g2 = h[(size_t)s2 * D1 + lane];
      float g3 = h[(size_t)s3 * D1 + lane];
      acc0 = fmaf(p0, g0, acc0);
      acc1 = fmaf(p1, g1, acc1);
      acc2 = fmaf(p2, g2, acc2);
      acc3 = fmaf(p3, g3, acc3);
      S += (p0 + p1) + (p2 + p3);
    }
    for (; j < cnt; ++j) {
      int s0 = __float_as_int(pw[j * 9 + 8]);
      float p0 = pw[j * 9 + hd];
      acc0 = fmaf(p0, h[(size_t)s0 * D1 + lane], acc0);
      S += p0;
    }
  }
  float acc = (acc0 + acc1) + (acc2 + acc3);
  x1[(size_t)n * D1 + lane] = eluf(acc / (S + 1e-16f) + b[lane]);
}

// ---- layer 2 linear: h2 = x1@W2 [N,40]; scalar logits [N] -----------------
__global__ void k_lin2(const float* __restrict__ x, const float* __restrict__ W,
                       const float* __restrict__ aw_s, const float* __restrict__ aw_d,
                       float* __restrict__ h, float* __restrict__ als, float* __restrict__ ald) {
  int lane = threadIdx.x;
  int cl = lane < NC ? lane : NC - 1;
  float wcol[D1];
  #pragma unroll
  for (int k = 0; k < D1; ++k) wcol[k] = W[k * NC + cl];
  float ws = aw_s[cl], wd = aw_d[cl];
  int n0 = blockIdx.x * NPB;
  for (int i = 0; i < NPB; ++i) {
    int n = n0 + i;
    if (n >= NN) return;
    const float* __restrict__ xr = x + (size_t)n * D1;
    float a0 = 0.f, a1 = 0.f, a2 = 0.f, a3 = 0.f;
    #pragma unroll
    for (int k = 0; k < D1; k += 4) {
      a0 = fmaf(xr[k + 0], wcol[k + 0], a0);
      a1 = fmaf(xr[k + 1], wcol[k + 1], a1);
      a2 = fmaf(xr[k + 2], wcol[k + 2], a2);
      a3 = fmaf(xr[k + 3], wcol[k + 3], a3);
    }
    float acc = (a0 + a1) + (a2 + a3);
    if (lane < NC) h[(size_t)n * NC + lane] = acc;
    float s = (lane < NC) ? acc * ws : 0.f;
    float d = (lane < NC) ? acc * wd : 0.f;
    #pragma unroll
    for (int off = 32; off >= 1; off >>= 1) {
      s += __shfl_xor(s, off);
      d += __shfl_xor(d, off);
    }
    if (lane == 0) { als[n] = s; ald[n] = d; }
  }
}

// ---- layer 2 fused single-pass aggregate, chunked wave-parallel ----------
// p is scalar per edge; pk+src staged in LDS (stride 3). Lanes >= NC clamp to
// col NC-1 (same-address broadcast: no extra cache lines, no divergence).
__global__ void k_node2(const int* __restrict__ row_start, const int* __restrict__ csr,
                        const float* __restrict__ h, const float* __restrict__ als,
                        const float* __restrict__ ald, const float* __restrict__ b,
                        float* __restrict__ out) {
  __shared__ float pl[4][64 * 3];
  int wid = threadIdx.x >> 6, lane = threadIdx.x & 63;
  int n = blockIdx.x * 4 + wid;
  if (n >= NN) return;
  float* pw = pl[wid];
  int r0 = row_start[n], r1 = row_start[n + 1];
  int cl = lane < NC ? lane : NC - 1;
  float aldn = ald[n];
  float S = 0.f, acc0 = 0.f, acc1 = 0.f, acc2 = 0.f, acc3 = 0.f;
  for (int kb = r0; kb < r1; kb += 64) {
    int cnt = min(64, r1 - kb);
    if (lane < cnt) {
      int sk = csr[kb + lane];
      pw[lane * 3 + 0] = __expf(leakyf(als[sk] + aldn));
      pw[lane * 3 + 1] = __int_as_float(sk);
    }
    asm volatile("s_waitcnt lgkmcnt(0)" ::: "memory");
    int j = 0;
    for (; j + 4 <= cnt; j += 4) {
      int s0 = __float_as_int(pw[(j + 0) * 3 + 1]);
      int s1 = __float_as_int(pw[(j + 1) * 3 + 1]);
      int s2 = __float_as_int(pw[(j + 2) * 3 + 1]);
      int s3 = __float_as_int(pw[(j + 3) * 3 + 1]);
      float p0 = pw[(j + 0) * 3], p1 = pw[(j + 1) * 3];
      float p2 = pw[(j + 2) * 3], p3 = pw[(j + 3) * 3];
      float g0 = h[(size_t)s0 * NC + cl];
      float g1 = h[(size_t)s1 * NC + cl];
      float g2 = h[(size_t)s2 * NC + cl];
      float g3 = h[(size_t)s3 * NC + cl];
      acc0 = fmaf(p0, g0, acc0);
      acc1 = fmaf(p1, g1, acc1);
      acc2 = fmaf(p2, g2, acc2);
      acc3 = fmaf(p3, g3, acc3);
      S += (p0 + p1) + (p2 + p3);
    }
    for (; j < cnt; ++j) {
      int s0 = __float_as_int(pw[j * 3 + 1]);
      float p0 = pw[j * 3];
      acc0 = fmaf(p0, h[(size_t)s0 * NC + cl], acc0);
      S += p0;
    }
  }
  float acc = (acc0 + acc1) + (acc2 + acc3);
  if (lane < NC) out[(size_t)n * NC + lane] = eluf(acc / (S + 1e-16f) + b[lane]);
}

extern "C" void kernel_launch(void* const* d_in, const int* in_sizes, int n_in,
                              void* d_out, int out_size, void* d_ws, size_t ws_size,
                              hipStream_t stream) {
  const float* x    = (const float*)d_in[0];
  const void*  ei   = d_in[1];
  const float* W1   = (const float*)d_in[3];
  const float* as1w = (const float*)d_in[4];
  const float* ad1w = (const float*)d_in[5];
  const float* b1   = (const float*)d_in[6];
  const float* W2   = (const float*)d_in[7];
  const float* as2w = (const float*)d_in[8];
  const float* ad2w = (const float*)d_in[9];
  const float* b2   = (const float*)d_in[10];
  float* out = (float*)d_out;

  char* w = (char*)d_ws;
  size_t off = 0;
  auto carve = [&](size_t bytes) -> void* {
    void* r = w + off;
    off += (bytes + 255) & ~(size_t)255;
    return r;
  };
  int*   ei32      = (int*)carve((size_t)2 * NE * 4);
  int*   flag      = (int*)carve(256);
  int*   deg       = (int*)carve((size_t)NN * 4);
  int*   row_start = (int*)carve((size_t)(NN + 1) * 4);
  int*   cursor    = (int*)carve((size_t)NN * 4);
  int*   bsum      = (int*)carve((size_t)NB_SCAN * 4);
  int*   boff      = (int*)carve((size_t)(NB_SCAN + 1) * 4);
  int*   csr       = (int*)carve((size_t)NETOT * 4);
  float* h1        = (float*)carve((size_t)NN * D1 * 4);   // reused as h2 [N,40]
  float* als1      = (float*)carve((size_t)NN * H1N * 4);  // reused as als2 [N]
  float* ald1      = (float*)carve((size_t)NN * H1N * 4);  // reused as ald2 [N]
  float* x1        = (float*)carve((size_t)NN * D1 * 4);
  float* h2 = h1; float* als2 = als1; float* ald2 = ald1;

  const int EB  = (NE + 255) / 256;
  const int LB  = (NN + NPB - 1) / NPB;

  // edge-index normalize
  k_detect<<<1, 64, 0, stream>>>((const long long*)ei, flag);
  k_convert<<<(2 * NE + 255) / 256, 256, 0, stream>>>(ei, flag, ei32, 2 * NE);

  // CSR build (by dst), self-loops pre-placed
  k_deginit<<<(NN + 255) / 256, 256, 0, stream>>>(deg);
  k_hist<<<EB, 256, 0, stream>>>(ei32, deg);
  k_chunksum<<<NB_SCAN, 256, 0, stream>>>(deg, bsum);
  k_scanbsum<<<1, 512, 0, stream>>>(bsum, boff);
  k_scanfinal<<<NB_SCAN, 256, 0, stream>>>(deg, boff, row_start, cursor, csr);
  k_scatter<<<EB, 256, 0, stream>>>(ei32, cursor, csr);

  // layer 1
  k_lin1<<<LB, 64, 0, stream>>>(x, W1, as1w, ad1w, h1, als1, ald1);
  k_node1<<<NN / 4, 256, 0, stream>>>(row_start, csr, h1, als1, ald1, b1, x1);

  // layer 2
  k_lin2<<<LB, 64, 0, stream>>>(x1, W2, as2w, ad2w, h2, als2, ald2);
  k_node2<<<NN / 4, 256, 0, stream>>>(row_start, csr, h2, als2, ald2, b2, out);
}

// Round 5
// 427.207 us; speedup vs baseline: 5.2863x; 1.2506x over previous
//
#include <hip/hip_runtime.h>
#include <math.h>

#define NN 100000
#define NE 1600000
#define NETOT (NE + NN)
#define FIN 128
#define H1N 8
#define D1 64
#define NC 40
#define NB_SCAN ((NN + 255) / 256)   // 391
#define LNT 64                        // nodes per tile in lin kernels

__device__ __forceinline__ float leakyf(float x) { return x >= 0.0f ? x : 0.2f * x; }
__device__ __forceinline__ float eluf(float x)   { return x > 0.0f ? x : expm1f(x); }

// ---- edge_index dtype detection (int64 vs int32) ------------------------
__global__ void k_detect(const long long* __restrict__ ei, int* __restrict__ flag) {
  if (blockIdx.x == 0 && threadIdx.x == 0) {
    int is64 = 1;
    for (int i = 0; i < 16; ++i) {
      long long v = ei[i];
      if (v < 0 || v >= NN) is64 = 0;
    }
    *flag = is64;
  }
}

__global__ void k_convert(const void* __restrict__ ei, const int* __restrict__ flag,
                          int* __restrict__ o, int n) {
  int i = blockIdx.x * blockDim.x + threadIdx.x;
  if (i >= n) return;
  o[i] = (*flag) ? (int)((const long long*)ei)[i] : ((const int*)ei)[i];
}

// ---- CSR build: histogram -> scan -> scatter -----------------------------
__global__ void k_deginit(int* __restrict__ deg) {       // self-loop pre-counted
  int i = blockIdx.x * blockDim.x + threadIdx.x;
  if (i < NN) deg[i] = 1;
}

__global__ void k_hist(const int* __restrict__ ei, int* __restrict__ deg) {
  int e = blockIdx.x * blockDim.x + threadIdx.x;
  if (e < NE) atomicAdd(&deg[ei[NE + e]], 1);
}

__global__ void k_chunksum(const int* __restrict__ deg, int* __restrict__ bsum) {
  __shared__ int sh[256];
  int t = threadIdx.x, i = blockIdx.x * 256 + t;
  sh[t] = (i < NN) ? deg[i] : 0;
  __syncthreads();
  for (int s = 128; s > 0; s >>= 1) { if (t < s) sh[t] += sh[t + s]; __syncthreads(); }
  if (t == 0) bsum[blockIdx.x] = sh[0];
}

__global__ void k_scanbsum(const int* __restrict__ bsum, int* __restrict__ boff) {
  __shared__ int sh[512];
  int t = threadIdx.x;
  int v = (t < NB_SCAN) ? bsum[t] : 0;
  sh[t] = v;
  __syncthreads();
  for (int s = 1; s < 512; s <<= 1) {
    int x = (t >= s) ? sh[t - s] : 0;
    __syncthreads();
    sh[t] += x;
    __syncthreads();
  }
  if (t < NB_SCAN) boff[t] = sh[t] - v;
  if (t == NB_SCAN - 1) boff[NB_SCAN] = sh[t];
}

__global__ void k_scanfinal(const int* __restrict__ deg, const int* __restrict__ boff,
                            int* __restrict__ row_start, int* __restrict__ cursor,
                            int* __restrict__ csr) {
  __shared__ int sh[256];
  int t = threadIdx.x, b = blockIdx.x, i = b * 256 + t;
  int v = (i < NN) ? deg[i] : 0;
  sh[t] = v;
  __syncthreads();
  for (int s = 1; s < 256; s <<= 1) {
    int x = (t >= s) ? sh[t - s] : 0;
    __syncthreads();
    sh[t] += x;
    __syncthreads();
  }
  if (i < NN) {
    int excl = boff[b] + sh[t] - v;
    row_start[i] = excl;
    csr[excl] = i;            // self-loop pre-placed
    cursor[i] = excl + 1;
    if (i == NN - 1) row_start[NN] = excl + v;
  }
}

__global__ void k_scatter(const int* __restrict__ ei, int* __restrict__ cursor,
                          int* __restrict__ csr) {
  int e = blockIdx.x * blockDim.x + threadIdx.x;
  if (e >= NE) return;
  int s = ei[e], d = ei[NE + e];
  int pos = atomicAdd(&cursor[d], 1);
  csr[pos] = s;
}

// ---- layer 1 linear: LDS-tiled GEMM h1 = x@W1 [N,64] + logits [N,8] ------
// block 256, tile 64 nodes. ws = W1 [128][64] (32KB); xs = x-tile, XOR-swizzled
// (k ^ (node&31)) so fixed-k column reads hit distinct banks (32KB). Thread
// (head=t&7, ng=t>>3) computes 2 nodes x 8 cols of one head -> head reduction
// is thread-local, als/ald written directly.
#define XS1(node, k) xs[(node) * FIN + ((k) ^ ((node) & 31))]
__global__ void k_lin1(const float* __restrict__ x, const float* __restrict__ W,
                       const float* __restrict__ aw_s, const float* __restrict__ aw_d,
                       float* __restrict__ h, float* __restrict__ als, float* __restrict__ ald) {
  __shared__ float ws[FIN * D1];
  __shared__ float xs[LNT * FIN];
  int t = threadIdx.x;
  int base = blockIdx.x * LNT;
  for (int i = t; i < FIN * D1; i += 256) ws[i] = W[i];
  for (int i = t; i < LNT * FIN; i += 256) {
    int node = i >> 7, k = i & 127;
    int gn = base + node;
    if (gn >= NN) gn = NN - 1;
    XS1(node, k) = x[(size_t)gn * FIN + k];
  }
  __syncthreads();
  int head = t & 7, ng = t >> 3;
  int n0l = ng * 2, n1l = n0l + 1;
  float acc0[8] = {0, 0, 0, 0, 0, 0, 0, 0};
  float acc1[8] = {0, 0, 0, 0, 0, 0, 0, 0};
  #pragma unroll 4
  for (int k = 0; k < FIN; ++k) {
    float x0 = XS1(n0l, k);
    float x1v = XS1(n1l, k);
    const float4* wr = (const float4*)&ws[k * D1 + head * 8];
    float4 wa = wr[0], wb = wr[1];
    acc0[0] = fmaf(x0, wa.x, acc0[0]); acc1[0] = fmaf(x1v, wa.x, acc1[0]);
    acc0[1] = fmaf(x0, wa.y, acc0[1]); acc1[1] = fmaf(x1v, wa.y, acc1[1]);
    acc0[2] = fmaf(x0, wa.z, acc0[2]); acc1[2] = fmaf(x1v, wa.z, acc1[2]);
    acc0[3] = fmaf(x0, wa.w, acc0[3]); acc1[3] = fmaf(x1v, wa.w, acc1[3]);
    acc0[4] = fmaf(x0, wb.x, acc0[4]); acc1[4] = fmaf(x1v, wb.x, acc1[4]);
    acc0[5] = fmaf(x0, wb.y, acc0[5]); acc1[5] = fmaf(x1v, wb.y, acc1[5]);
    acc0[6] = fmaf(x0, wb.z, acc0[6]); acc1[6] = fmaf(x1v, wb.z, acc1[6]);
    acc0[7] = fmaf(x0, wb.w, acc0[7]); acc1[7] = fmaf(x1v, wb.w, acc1[7]);
  }
  int n0 = base + n0l, n1 = base + n1l;
  float aws[8], awd[8];
  #pragma unroll
  for (int c = 0; c < 8; ++c) { aws[c] = aw_s[head * 8 + c]; awd[c] = aw_d[head * 8 + c]; }
  if (n0 < NN) {
    float s = 0.f, d = 0.f;
    #pragma unroll
    for (int c = 0; c < 8; ++c) {
      h[(size_t)n0 * D1 + head * 8 + c] = acc0[c];
      s = fmaf(acc0[c], aws[c], s);
      d = fmaf(acc0[c], awd[c], d);
    }
    als[n0 * H1N + head] = s;
    ald[n0 * H1N + head] = d;
  }
  if (n1 < NN) {
    float s = 0.f, d = 0.f;
    #pragma unroll
    for (int c = 0; c < 8; ++c) {
      h[(size_t)n1 * D1 + head * 8 + c] = acc1[c];
      s = fmaf(acc1[c], aws[c], s);
      d = fmaf(acc1[c], awd[c], d);
    }
    als[n1 * H1N + head] = s;
    ald[n1 * H1N + head] = d;
  }
}

// ---- layer 2 linear: LDS-tiled GEMM h2 = x1@W2 [N,40] + scalar logits ----
// W2 zero-padded to [64][64] in LDS; col-group g=t&7 (groups 5..7 compute
// zeros); logit reduce = 3-step shfl_xor over the 8-lane node group.
#define XS2(node, k) xs[(node) * D1 + ((k) ^ ((node) & 31))]
__global__ void k_lin2(const float* __restrict__ x, const float* __restrict__ W,
                       const float* __restrict__ aw_s, const float* __restrict__ aw_d,
                       float* __restrict__ h, float* __restrict__ als, float* __restrict__ ald) {
  __shared__ float ws[D1 * D1];
  __shared__ float xs[LNT * D1];
  int t = threadIdx.x;
  int base = blockIdx.x * LNT;
  for (int i = t; i < D1 * D1; i += 256) {
    int k = i >> 6, c = i & 63;
    ws[i] = (c < NC) ? W[k * NC + c] : 0.f;
  }
  for (int i = t; i < LNT * D1; i += 256) {
    int node = i >> 6, k = i & 63;
    int gn = base + node;
    if (gn >= NN) gn = NN - 1;
    XS2(node, k) = x[(size_t)gn * D1 + k];
  }
  __syncthreads();
  int g = t & 7, ng = t >> 3;
  int n0l = ng * 2, n1l = n0l + 1;
  float acc0[8] = {0, 0, 0, 0, 0, 0, 0, 0};
  float acc1[8] = {0, 0, 0, 0, 0, 0, 0, 0};
  #pragma unroll 4
  for (int k = 0; k < D1; ++k) {
    float x0 = XS2(n0l, k);
    float x1v = XS2(n1l, k);
    const float4* wr = (const float4*)&ws[k * D1 + g * 8];
    float4 wa = wr[0], wb = wr[1];
    acc0[0] = fmaf(x0, wa.x, acc0[0]); acc1[0] = fmaf(x1v, wa.x, acc1[0]);
    acc0[1] = fmaf(x0, wa.y, acc0[1]); acc1[1] = fmaf(x1v, wa.y, acc1[1]);
    acc0[2] = fmaf(x0, wa.z, acc0[2]); acc1[2] = fmaf(x1v, wa.z, acc1[2]);
    acc0[3] = fmaf(x0, wa.w, acc0[3]); acc1[3] = fmaf(x1v, wa.w, acc1[3]);
    acc0[4] = fmaf(x0, wb.x, acc0[4]); acc1[4] = fmaf(x1v, wb.x, acc1[4]);
    acc0[5] = fmaf(x0, wb.y, acc0[5]); acc1[5] = fmaf(x1v, wb.y, acc1[5]);
    acc0[6] = fmaf(x0, wb.z, acc0[6]); acc1[6] = fmaf(x1v, wb.z, acc1[6]);
    acc0[7] = fmaf(x0, wb.w, acc0[7]); acc1[7] = fmaf(x1v, wb.w, acc1[7]);
  }
  int n0 = base + n0l, n1 = base + n1l;
  float aws[8], awd[8];
  #pragma unroll
  for (int c = 0; c < 8; ++c) {
    int col = g * 8 + c;
    aws[c] = (col < NC) ? aw_s[col] : 0.f;
    awd[c] = (col < NC) ? aw_d[col] : 0.f;
  }
  float s0 = 0.f, d0 = 0.f, s1 = 0.f, d1 = 0.f;
  #pragma unroll
  for (int c = 0; c < 8; ++c) {
    s0 = fmaf(acc0[c], aws[c], s0); d0 = fmaf(acc0[c], awd[c], d0);
    s1 = fmaf(acc1[c], aws[c], s1); d1 = fmaf(acc1[c], awd[c], d1);
  }
  s0 += __shfl_xor(s0, 1); d0 += __shfl_xor(d0, 1); s1 += __shfl_xor(s1, 1); d1 += __shfl_xor(d1, 1);
  s0 += __shfl_xor(s0, 2); d0 += __shfl_xor(d0, 2); s1 += __shfl_xor(s1, 2); d1 += __shfl_xor(d1, 2);
  s0 += __shfl_xor(s0, 4); d0 += __shfl_xor(d0, 4); s1 += __shfl_xor(s1, 4); d1 += __shfl_xor(d1, 4);
  if (n0 < NN && g < 5) {
    #pragma unroll
    for (int c = 0; c < 8; ++c) h[(size_t)n0 * NC + g * 8 + c] = acc0[c];
  }
  if (n1 < NN && g < 5) {
    #pragma unroll
    for (int c = 0; c < 8; ++c) h[(size_t)n1 * NC + g * 8 + c] = acc1[c];
  }
  if (g == 0) {
    if (n0 < NN) { als[n0] = s0; ald[n0] = d0; }
    if (n1 < NN) { als[n1] = s1; ald[n1] = d1; }
  }
}

// ---- layer 1 fused single-pass aggregate, chunked wave-parallel ----------
__global__ void k_node1(const int* __restrict__ row_start, const int* __restrict__ csr,
                        const float* __restrict__ h, const float* __restrict__ als,
                        const float* __restrict__ ald, const float* __restrict__ b,
                        float* __restrict__ x1) {
  __shared__ float pl[4][64 * 9];
  int wid = threadIdx.x >> 6, lane = threadIdx.x & 63;
  int n = blockIdx.x * 4 + wid;
  if (n >= NN) return;
  float* pw = pl[wid];
  int r0 = row_start[n], r1 = row_start[n + 1];
  int hd = lane >> 3;
  const float4* adp = (const float4*)(ald + (size_t)n * H1N);
  float4 ad0 = adp[0], ad1 = adp[1];
  float S = 0.f, acc0 = 0.f, acc1 = 0.f, acc2 = 0.f, acc3 = 0.f;
  for (int kb = r0; kb < r1; kb += 64) {
    int cnt = min(64, r1 - kb);
    if (lane < cnt) {
      int sk = csr[kb + lane];
      const float4* ap = (const float4*)(als + (size_t)sk * H1N);
      float4 a0 = ap[0], a1 = ap[1];
      pw[lane * 9 + 0] = __expf(leakyf(a0.x + ad0.x));
      pw[lane * 9 + 1] = __expf(leakyf(a0.y + ad0.y));
      pw[lane * 9 + 2] = __expf(leakyf(a0.z + ad0.z));
      pw[lane * 9 + 3] = __expf(leakyf(a0.w + ad0.w));
      pw[lane * 9 + 4] = __expf(leakyf(a1.x + ad1.x));
      pw[lane * 9 + 5] = __expf(leakyf(a1.y + ad1.y));
      pw[lane * 9 + 6] = __expf(leakyf(a1.z + ad1.z));
      pw[lane * 9 + 7] = __expf(leakyf(a1.w + ad1.w));
      pw[lane * 9 + 8] = __int_as_float(sk);
    }
    asm volatile("s_waitcnt lgkmcnt(0)" ::: "memory");   // wave-internal LDS RAW
    int j = 0;
    for (; j + 4 <= cnt; j += 4) {
      int s0 = __float_as_int(pw[(j + 0) * 9 + 8]);
      int s1 = __float_as_int(pw[(j + 1) * 9 + 8]);
      int s2 = __float_as_int(pw[(j + 2) * 9 + 8]);
      int s3 = __float_as_int(pw[(j + 3) * 9 + 8]);
      float p0 = pw[(j + 0) * 9 + hd], p1 = pw[(j + 1) * 9 + hd];
      float p2 = pw[(j + 2) * 9 + hd], p3 = pw[(j + 3) * 9 + hd];
      float g0 = h[(size_t)s0 * D1 + lane];
      float g1 = h[(size_t)s1 * D1 + lane];
      float g2 = h[(size_t)s2 * D1 + lane];
      float g3 = h[(size_t)s3 * D1 + lane];
      acc0 = fmaf(p0, g0, acc0);
      acc1 = fmaf(p1, g1, acc1);
      acc2 = fmaf(p2, g2, acc2);
      acc3 = fmaf(p3, g3, acc3);
      S += (p0 + p1) + (p2 + p3);
    }
    for (; j < cnt; ++j) {
      int s0 = __float_as_int(pw[j * 9 + 8]);
      float p0 = pw[j * 9 + hd];
      acc0 = fmaf(p0, h[(size_t)s0 * D1 + lane], acc0);
      S += p0;
    }
  }
  float acc = (acc0 + acc1) + (acc2 + acc3);
  x1[(size_t)n * D1 + lane] = eluf(acc / (S + 1e-16f) + b[lane]);
}

// ---- layer 2 fused single-pass aggregate, chunked wave-parallel ----------
__global__ void k_node2(const int* __restrict__ row_start, const int* __restrict__ csr,
                        const float* __restrict__ h, const float* __restrict__ als,
                        const float* __restrict__ ald, const float* __restrict__ b,
                        float* __restrict__ out) {
  __shared__ float pl[4][64 * 3];
  int wid = threadIdx.x >> 6, lane = threadIdx.x & 63;
  int n = blockIdx.x * 4 + wid;
  if (n >= NN) return;
  float* pw = pl[wid];
  int r0 = row_start[n], r1 = row_start[n + 1];
  int cl = lane < NC ? lane : NC - 1;
  float aldn = ald[n];
  float S = 0.f, acc0 = 0.f, acc1 = 0.f, acc2 = 0.f, acc3 = 0.f;
  for (int kb = r0; kb < r1; kb += 64) {
    int cnt = min(64, r1 - kb);
    if (lane < cnt) {
      int sk = csr[kb + lane];
      pw[lane * 3 + 0] = __expf(leakyf(als[sk] + aldn));
      pw[lane * 3 + 1] = __int_as_float(sk);
    }
    asm volatile("s_waitcnt lgkmcnt(0)" ::: "memory");
    int j = 0;
    for (; j + 4 <= cnt; j += 4) {
      int s0 = __float_as_int(pw[(j + 0) * 3 + 1]);
      int s1 = __float_as_int(pw[(j + 1) * 3 + 1]);
      int s2 = __float_as_int(pw[(j + 2) * 3 + 1]);
      int s3 = __float_as_int(pw[(j + 3) * 3 + 1]);
      float p0 = pw[(j + 0) * 3], p1 = pw[(j + 1) * 3];
      float p2 = pw[(j + 2) * 3], p3 = pw[(j + 3) * 3];
      float g0 = h[(size_t)s0 * NC + cl];
      float g1 = h[(size_t)s1 * NC + cl];
      float g2 = h[(size_t)s2 * NC + cl];
      float g3 = h[(size_t)s3 * NC + cl];
      acc0 = fmaf(p0, g0, acc0);
      acc1 = fmaf(p1, g1, acc1);
      acc2 = fmaf(p2, g2, acc2);
      acc3 = fmaf(p3, g3, acc3);
      S += (p0 + p1) + (p2 + p3);
    }
    for (; j < cnt; ++j) {
      int s0 = __float_as_int(pw[j * 3 + 1]);
      float p0 = pw[j * 3];
      acc0 = fmaf(p0, h[(size_t)s0 * NC + cl], acc0);
      S += p0;
    }
  }
  float acc = (acc0 + acc1) + (acc2 + acc3);
  if (lane < NC) out[(size_t)n * NC + lane] = eluf(acc / (S + 1e-16f) + b[lane]);
}

extern "C" void kernel_launch(void* const* d_in, const int* in_sizes, int n_in,
                              void* d_out, int out_size, void* d_ws, size_t ws_size,
                              hipStream_t stream) {
  const float* x    = (const float*)d_in[0];
  const void*  ei   = d_in[1];
  const float* W1   = (const float*)d_in[3];
  const float* as1w = (const float*)d_in[4];
  const float* ad1w = (const float*)d_in[5];
  const float* b1   = (const float*)d_in[6];
  const float* W2   = (const float*)d_in[7];
  const float* as2w = (const float*)d_in[8];
  const float* ad2w = (const float*)d_in[9];
  const float* b2   = (const float*)d_in[10];
  float* out = (float*)d_out;

  char* w = (char*)d_ws;
  size_t off = 0;
  auto carve = [&](size_t bytes) -> void* {
    void* r = w + off;
    off += (bytes + 255) & ~(size_t)255;
    return r;
  };
  int*   ei32      = (int*)carve((size_t)2 * NE * 4);
  int*   flag      = (int*)carve(256);
  int*   deg       = (int*)carve((size_t)NN * 4);
  int*   row_start = (int*)carve((size_t)(NN + 1) * 4);
  int*   cursor    = (int*)carve((size_t)NN * 4);
  int*   bsum      = (int*)carve((size_t)NB_SCAN * 4);
  int*   boff      = (int*)carve((size_t)(NB_SCAN + 1) * 4);
  int*   csr       = (int*)carve((size_t)NETOT * 4);
  float* h1        = (float*)carve((size_t)NN * D1 * 4);   // reused as h2 [N,40]
  float* als1      = (float*)carve((size_t)NN * H1N * 4);  // reused as als2 [N]
  float* ald1      = (float*)carve((size_t)NN * H1N * 4);  // reused as ald2 [N]
  float* x1        = (float*)carve((size_t)NN * D1 * 4);
  float* h2 = h1; float* als2 = als1; float* ald2 = ald1;

  const int EB = (NE + 255) / 256;
  const int LB = (NN + LNT - 1) / LNT;

  // edge-index normalize
  k_detect<<<1, 64, 0, stream>>>((const long long*)ei, flag);
  k_convert<<<(2 * NE + 255) / 256, 256, 0, stream>>>(ei, flag, ei32, 2 * NE);

  // CSR build (by dst), self-loops pre-placed
  k_deginit<<<(NN + 255) / 256, 256, 0, stream>>>(deg);
  k_hist<<<EB, 256, 0, stream>>>(ei32, deg);
  k_chunksum<<<NB_SCAN, 256, 0, stream>>>(deg, bsum);
  k_scanbsum<<<1, 512, 0, stream>>>(bsum, boff);
  k_scanfinal<<<NB_SCAN, 256, 0, stream>>>(deg, boff, row_start, cursor, csr);
  k_scatter<<<EB, 256, 0, stream>>>(ei32, cursor, csr);

  // layer 1
  k_lin1<<<LB, 256, 0, stream>>>(x, W1, as1w, ad1w, h1, als1, ald1);
  k_node1<<<NN / 4, 256, 0, stream>>>(row_start, csr, h1, als1, ald1, b1, x1);

  // layer 2
  k_lin2<<<LB, 256, 0, stream>>>(x1, W2, as2w, ad2w, h2, als2, ald2);
  k_node2<<<NN / 4, 256, 0, stream>>>(row_start, csr, h2, als2, ald2, b2, out);
}